// Round 9
// baseline (337.131 us; speedup 1.0000x reference)
//
#include <hip/hip_runtime.h>
#include <hip/hip_bf16.h>

#define B_   32
#define L_   2048
#define CIN  256
#define HID  512
#define TL   32
#define NLT  (L_ / TL)        // 64 tiles of 32 rows per batch
#define NTILES (B_ * NLT)     // 2048
#define TPB  8                // tiles per persistent block
#define NBLK (NTILES / TPB)   // 256 blocks = 1 per CU

typedef __bf16 bf16_t;
typedef __bf16 bf16x8 __attribute__((ext_vector_type(8)));
typedef __bf16 bf16x4 __attribute__((ext_vector_type(4)));
typedef float  f32x4  __attribute__((ext_vector_type(4)));

// LDS map (128 KB), NO aliasing:
//   A double-buffer: buf b @ b*32768 (x-pipe @ +0, y-pipe @ +16384; rows 512B)
//   Hx @ 65536 (32 rows x 1024B), Hy @ 98304
#define APIPE  16384u
#define HX_OFF 65536u
#define HY_OFF 98304u

// lgkmcnt-only barrier: drains LDS ops, leaves global loads in flight.
__device__ __forceinline__ void lgkm_bar() {
    asm volatile("s_waitcnt lgkmcnt(0)\n\ts_barrier" ::: "memory");
}

// ---------------------------------------------------------------------------
// Kernel 1: cast weights fp32 -> bf16 into workspace
// ---------------------------------------------------------------------------
__global__ void cast_weights_kernel(const float* __restrict__ W1, const float* __restrict__ W2,
                                    bf16_t* __restrict__ W1b, bf16_t* __restrict__ W2b)
{
    int i = blockIdx.x * blockDim.x + threadIdx.x;
    if (i < HID * CIN) W1b[i] = (bf16_t)W1[i];
    if (i < HID * HID) W2b[i] = (bf16_t)W2[i];
}

// ---------------------------------------------------------------------------
// Kernel 2: persistent fused kernel. 256 blocks x 1024 thr (16 waves), 8
// 32-row tiles per block. Wave w owns cols [w*32,w*32+32), rows 0..31, BOTH
// pipes -> acc = 32 AGPR only (the R2/R5/R6/R8 spill fix: arch cap now 96).
// A double-buffered => tile t+1's fp32 loads (v[4], 16 regs) issue at tile
// start and ds_write into the idle buffer after gemm2 — transfer fully
// hidden under ~6us of compute. 2 barriers per tile (H-ready, tile-end).
// Swapped-operand MFMA (D.m = H-col), biases folded into acc init, paired
// tanh; psum accumulates across all 8 tiles.
// ---------------------------------------------------------------------------
__global__ __launch_bounds__(1024, 4)
void fused_proj_kernel(const float* __restrict__ x, const float* __restrict__ y,
                       const bf16_t* __restrict__ W1b, const float* __restrict__ b1,
                       const bf16_t* __restrict__ W2b, const float* __restrict__ b2,
                       float* __restrict__ partial)
{
    __shared__ char U[131072];           // 128 KB

    const int tid  = threadIdx.x;
    const int lane = tid & 63;
    const int wv   = tid >> 6;           // wave 0..15
    const int l15  = lane & 15;
    const int l4   = lane >> 4;
    const int col0 = wv * 32;            // this wave's output-col base

    // staging identity: threads 0-511 stage x, 512-1023 stage y; 16 thr/row
    const int sp   = tid >> 9;
    const int t9   = tid & 511;
    const int srow = t9 >> 4;            // row 0..31
    const int sq   = t9 & 15;            // float4 slot
    const unsigned sswz   = (unsigned)((srow & 15) << 4);
    const unsigned sldsrow = (sp ? APIPE : 0u) + (unsigned)(srow * 512);

    const int tile0 = blockIdx.x * TPB;  // global row = tile*32 + srow (contiguous)
    const float* sptr = (sp ? y : x) + ((size_t)(tile0 * TL + srow)) * CIN;

    float4 v[4];
    auto sload = [&](const float* rowbase) {
        const float4* s4 = reinterpret_cast<const float4*>(rowbase);
#pragma unroll
        for (int c = 0; c < 4; ++c) v[c] = s4[sq + 16 * c];
    };
    auto swrite = [&](int buf) {
        char* p = U + (unsigned)(buf * 32768) + sldsrow;
#pragma unroll
        for (int c = 0; c < 4; ++c) {
            const int f = sq + 16 * c;
            bf16x4 h;
            h[0] = (bf16_t)v[c].x; h[1] = (bf16_t)v[c].y;
            h[2] = (bf16_t)v[c].z; h[3] = (bf16_t)v[c].w;
            *reinterpret_cast<bf16x4*>(p + (((unsigned)(8 * f)) ^ sswz)) = h;
        }
    };

    // fragment base offsets; per-kk address = base ^ (kk<<6) (disjoint bits,
    // proven pattern from R4/R7)
    unsigned abase[2], hbase[2];
#pragma unroll
    for (int ri = 0; ri < 2; ++ri) {
        const int r = ri * 16 + l15;
        const unsigned swz = (unsigned)((r & 15) << 4);
        abase[ri] = (unsigned)(r * 512)  + (((unsigned)(l4 * 16)) ^ swz);
        hbase[ri] = (unsigned)(r * 1024) + (((unsigned)(l4 * 16)) ^ swz);
    }

    f32x4 psum[2];
    psum[0] = (f32x4){0.f, 0.f, 0.f, 0.f};
    psum[1] = (f32x4){0.f, 0.f, 0.f, 0.f};

    // prologue: stage tile0 into buf0
    sload(sptr);
    swrite(0);
    lgkm_bar();

    int cur = 0;
    for (int t = 0; t < TPB; ++t) {
        if (t + 1 < TPB) {               // issue tile t+1 loads NOW (T14);
            sptr += TL * CIN;            // consumed by swrite after gemm2
            sload(sptr);
        }

        // ---- GEMM1 both pipes (shared W1 stream), bias b1 in acc init
        f32x4 accx[2][2], accy[2][2];
#pragma unroll
        for (int cj = 0; cj < 2; ++cj) {
            float4 bv = *reinterpret_cast<const float4*>(b1 + col0 + cj * 16 + l4 * 4);
            f32x4 bi = (f32x4){bv.x, bv.y, bv.z, bv.w};
#pragma unroll
            for (int ri = 0; ri < 2; ++ri) { accx[ri][cj] = bi; accy[ri][cj] = bi; }
        }
        for (int kk = 0; kk < CIN / 32; ++kk) {
            bf16x8 w[2];
#pragma unroll
            for (int cj = 0; cj < 2; ++cj)
                w[cj] = *reinterpret_cast<const bf16x8*>(
                    W1b + (size_t)(col0 + cj * 16 + l15) * CIN + kk * 32 + l4 * 8);
            __builtin_amdgcn_s_setprio(1);
#pragma unroll
            for (int ri = 0; ri < 2; ++ri) {
                unsigned o = abase[ri] ^ (unsigned)(kk << 6);
                bf16x8 ax = *reinterpret_cast<const bf16x8*>(U + (unsigned)(cur * 32768) + o);
                bf16x8 ay = *reinterpret_cast<const bf16x8*>(U + (unsigned)(cur * 32768) + APIPE + o);
#pragma unroll
                for (int cj = 0; cj < 2; ++cj) {
                    accx[ri][cj] = __builtin_amdgcn_mfma_f32_16x16x32_bf16(w[cj], ax, accx[ri][cj], 0, 0, 0);
                    accy[ri][cj] = __builtin_amdgcn_mfma_f32_16x16x32_bf16(w[cj], ay, accy[ri][cj], 0, 0, 0);
                }
            }
            __builtin_amdgcn_s_setprio(0);
        }

        // ---- writeH (packed bf16x4). H(t-1) readers finished at B3(t-1).
#pragma unroll
        for (int ri = 0; ri < 2; ++ri) {
            const int r = ri * 16 + l15;
            const unsigned swz = (unsigned)((r & 15) << 4);
#pragma unroll
            for (int cj = 0; cj < 2; ++cj) {
                unsigned off = (unsigned)(r * 1024) +
                               (((unsigned)((col0 + cj * 16 + l4 * 4) * 2)) ^ swz);
                bf16x4 px, py;
#pragma unroll
                for (int r2 = 0; r2 < 4; ++r2) {
                    px[r2] = (bf16_t)accx[ri][cj][r2];
                    py[r2] = (bf16_t)accy[ri][cj][r2];
                }
                *reinterpret_cast<bf16x4*>(U + HX_OFF + off) = px;
                *reinterpret_cast<bf16x4*>(U + HY_OFF + off) = py;
            }
        }
        lgkm_bar();                      // B1: H visible to all waves

        // ---- GEMM2 both pipes (shared W2 stream), bias b2 in acc init
        f32x4 cx[2][2], cy[2][2];
#pragma unroll
        for (int cj = 0; cj < 2; ++cj) {
            float4 bv = *reinterpret_cast<const float4*>(b2 + col0 + cj * 16 + l4 * 4);
            f32x4 bi = (f32x4){bv.x, bv.y, bv.z, bv.w};
#pragma unroll
            for (int ri = 0; ri < 2; ++ri) { cx[ri][cj] = bi; cy[ri][cj] = bi; }
        }
        for (int kk = 0; kk < HID / 32; ++kk) {
            bf16x8 w[2];
#pragma unroll
            for (int cj = 0; cj < 2; ++cj)
                w[cj] = *reinterpret_cast<const bf16x8*>(
                    W2b + (size_t)(col0 + cj * 16 + l15) * HID + kk * 32 + l4 * 8);
            __builtin_amdgcn_s_setprio(1);
#pragma unroll
            for (int ri = 0; ri < 2; ++ri) {
                unsigned o = hbase[ri] ^ (unsigned)(kk << 6);
                bf16x8 px = *reinterpret_cast<const bf16x8*>(U + HX_OFF + o);
                bf16x8 py = *reinterpret_cast<const bf16x8*>(U + HY_OFF + o);
#pragma unroll
                for (int cj = 0; cj < 2; ++cj) {
                    cx[ri][cj] = __builtin_amdgcn_mfma_f32_16x16x32_bf16(w[cj], px, cx[ri][cj], 0, 0, 0);
                    cy[ri][cj] = __builtin_amdgcn_mfma_f32_16x16x32_bf16(w[cj], py, cy[ri][cj], 0, 0, 0);
                }
            }
            __builtin_amdgcn_s_setprio(0);
        }

        // ---- write staged tile t+1 into the idle A buffer (no hazard: that
        // buffer's readers finished before B1(t); drained by B3's lgkm)
        if (t + 1 < TPB) swrite(cur ^ 1);

        // ---- paired tanh product, accumulate into psum (VALU overlaps the
        // ds_writes above). tanh(a)tanh(b) = (Ea-1)(Eb-1)/((Ea+1)(Eb+1)).
#pragma unroll
        for (int ri = 0; ri < 2; ++ri)
#pragma unroll
            for (int cj = 0; cj < 2; ++cj)
#pragma unroll
                for (int r2 = 0; r2 < 4; ++r2) {
                    float a = fminf(fmaxf(cx[ri][cj][r2], -9.0f), 9.0f);
                    float c = fminf(fmaxf(cy[ri][cj][r2], -9.0f), 9.0f);
                    float Ea = exp2f(a * 2.885390081777927f);
                    float Eb = exp2f(c * 2.885390081777927f);
                    float num = (Ea - 1.0f) * (Eb - 1.0f);
                    float den = (Ea + 1.0f) * (Eb + 1.0f);
                    psum[cj][r2] += num * __builtin_amdgcn_rcpf(den);
                }

        lgkm_bar();                      // B3: tile end (A[next]+H hazards)
        cur ^= 1;
    }

    // ---- final row-reduction over l15 lanes + one store per block
#pragma unroll
    for (int cj = 0; cj < 2; ++cj)
#pragma unroll
        for (int r2 = 0; r2 < 4; ++r2) {
            float s = psum[cj][r2];
            s += __shfl_xor(s, 1);
            s += __shfl_xor(s, 2);
            s += __shfl_xor(s, 4);
            s += __shfl_xor(s, 8);
            psum[cj][r2] = s;
        }
    if (l15 == 0) {
#pragma unroll
        for (int cj = 0; cj < 2; ++cj) {
            float4 o = make_float4(psum[cj][0], psum[cj][1], psum[cj][2], psum[cj][3]);
            *reinterpret_cast<float4*>(partial + (size_t)blockIdx.x * HID + col0 + cj * 16 + l4 * 4) = o;
        }
    }
}

// ---------------------------------------------------------------------------
// Kernel 3: sum the 8 block-partials per batch -> out[B][HID]
// ---------------------------------------------------------------------------
__global__ void reduce_kernel(const float* __restrict__ partial, float* __restrict__ out)
{
    int b = blockIdx.x;
    int g = threadIdx.x;             // 512 threads
    float s = 0.f;
#pragma unroll
    for (int k = 0; k < TPB; ++k)
        s += partial[((size_t)(b * TPB + k)) * HID + g];
    out[b * HID + g] = s;
}

extern "C" void kernel_launch(void* const* d_in, const int* in_sizes, int n_in,
                              void* d_out, int out_size, void* d_ws, size_t ws_size,
                              hipStream_t stream)
{
    const float* x  = (const float*)d_in[0];
    const float* y  = (const float*)d_in[1];
    const float* W1 = (const float*)d_in[2];
    const float* b1 = (const float*)d_in[3];
    const float* W2 = (const float*)d_in[4];
    const float* b2 = (const float*)d_in[5];
    float* out = (float*)d_out;

    char* ws = (char*)d_ws;
    bf16_t* W1b    = (bf16_t*)ws;                    // 256 KB
    bf16_t* W2b    = (bf16_t*)(ws + (256 << 10));    // 512 KB
    float*  partial = (float*)(ws + (768 << 10));    // 512 KB (256 blocks x 512)

    hipLaunchKernelGGL(cast_weights_kernel, dim3(1024), dim3(256), 0, stream, W1, W2, W1b, W2b);
    hipLaunchKernelGGL(fused_proj_kernel, dim3(NBLK), dim3(1024), 0, stream,
                       x, y, W1b, b1, W2b, b2, partial);
    hipLaunchKernelGGL(reduce_kernel, dim3(B_), dim3(512), 0, stream, partial, out);
}